// Round 6
// baseline (271.180 us; speedup 1.0000x reference)
//
#include <hip/hip_runtime.h>
#include <hip/hip_bf16.h>
#include <math.h>

// ---------------------------------------------------------------------------
// GraphConv GNN, round 5: lane-parallel multi-edge gather (4 edges/step at
// C=128, 2 edges/step at C=256) + shfl_xor edge-slot reduction.
// ---------------------------------------------------------------------------

typedef __attribute__((ext_vector_type(8))) short short8;
typedef __attribute__((ext_vector_type(4))) float f32x4;

static __device__ __forceinline__ float bf2f(unsigned short u) {
    return __uint_as_float(((unsigned)u) << 16);
}

// ---- CSR scan -------------------------------------------------------------
__global__ __launch_bounds__(256) void scan_block_sums(
    const int* __restrict__ counts, int* __restrict__ bsum, int n)
{
    __shared__ int sh[256];
    int idx = blockIdx.x * 256 + threadIdx.x;
    sh[threadIdx.x] = (idx < n) ? counts[idx] : 0;
    __syncthreads();
#pragma unroll
    for (int off = 128; off; off >>= 1) {
        if (threadIdx.x < off) sh[threadIdx.x] += sh[threadIdx.x + off];
        __syncthreads();
    }
    if (threadIdx.x == 0) bsum[blockIdx.x] = sh[0];
}

__global__ __launch_bounds__(256) void scan_bsum(
    const int* __restrict__ bsum, int* __restrict__ bpre, int nb)
{
    __shared__ int sh[256];
    int t = threadIdx.x;
    int v = (t < nb) ? bsum[t] : 0;
    sh[t] = v;
    __syncthreads();
#pragma unroll
    for (int off = 1; off < 256; off <<= 1) {
        int u = (t >= off) ? sh[t - off] : 0;
        __syncthreads();
        sh[t] += u;
        __syncthreads();
    }
    bpre[t] = sh[t] - v;   // exclusive
}

__global__ __launch_bounds__(256) void scan_final(
    const int* __restrict__ counts, const int* __restrict__ bpre,
    int* __restrict__ row_ptr, int* __restrict__ cursor, int n, int Etot)
{
    __shared__ int sh[256];
    int t = threadIdx.x;
    int idx = blockIdx.x * 256 + t;
    int v = (idx < n) ? counts[idx] : 0;
    sh[t] = v;
    __syncthreads();
#pragma unroll
    for (int off = 1; off < 256; off <<= 1) {
        int u = (t >= off) ? sh[t - off] : 0;
        __syncthreads();
        sh[t] += u;
        __syncthreads();
    }
    if (idx < n) {
        int val = bpre[blockIdx.x] + sh[t] - v;
        row_ptr[idx] = val;
        cursor[idx]  = val;
    }
    if (idx == 0) row_ptr[n] = Etot;
}

__global__ __launch_bounds__(256) void fill_kernel(
    const int* __restrict__ ei, const float* __restrict__ ew,
    int* __restrict__ cursor, int2* __restrict__ edges, int E)
{
    int e = blockIdx.x * 256 + threadIdx.x;
    if (e >= E) return;
    int d = ei[E + e];
    int p = atomicAdd(&cursor[d], 1);
    edges[p] = make_int2(ei[e], __float_as_int(ew[e]));
}

// ---- fused prep: count atomics + x->bf16 + weight transposes --------------
__global__ __launch_bounds__(256) void prep_all(
    const int* __restrict__ ei, int* __restrict__ counts, int E,
    const float* __restrict__ x, __hip_bfloat16* __restrict__ xb, int NX8,
    const float* __restrict__ w1_rel, const float* __restrict__ w1_root,
    const float* __restrict__ w2_rel, const float* __restrict__ w2_root,
    const float* __restrict__ w_lin,
    __hip_bfloat16* __restrict__ w1relT, __hip_bfloat16* __restrict__ w1rootT,
    __hip_bfloat16* __restrict__ w2relT, __hip_bfloat16* __restrict__ w2rootT,
    __hip_bfloat16* __restrict__ wlinT)
{
    int idx = blockIdx.x * 256 + threadIdx.x;
    if (idx < E) {
        atomicAdd(&counts[ei[E + idx]], 1);
        return;
    }
    idx -= E;
    if (idx < NX8) {   // x -> bf16, 8 elems/thread
        float4 a = *(const float4*)&x[(size_t)idx * 8];
        float4 b = *(const float4*)&x[(size_t)idx * 8 + 4];
        __hip_bfloat16 o[8] = {
            __float2bfloat16(a.x), __float2bfloat16(a.y),
            __float2bfloat16(a.z), __float2bfloat16(a.w),
            __float2bfloat16(b.x), __float2bfloat16(b.y),
            __float2bfloat16(b.z), __float2bfloat16(b.w) };
        *(short8*)&xb[(size_t)idx * 8] = *(short8*)o;
        return;
    }
    idx -= NX8;
    if (idx < 65536) {                       // w1_rel/w1_root [128,256] -> [256,128]
        const float* src = (idx < 32768) ? w1_rel : w1_root;
        __hip_bfloat16* dst = (idx < 32768) ? w1relT : w1rootT;
        int i = idx & 32767;
        int k = i >> 8, c = i & 255;
        dst[c * 128 + k] = __float2bfloat16(src[i]);
    } else if (idx < 196608) {               // w2_rel/w2_root [256,256]^T
        int j = idx - 65536;
        const float* src = (j < 65536) ? w2_rel : w2_root;
        __hip_bfloat16* dst = (j < 65536) ? w2relT : w2rootT;
        int i = j & 65535;
        int k = i >> 8, c = i & 255;
        dst[c * 256 + k] = __float2bfloat16(src[i]);
    } else if (idx < 229376) {               // w_lin [512,40] -> [2][64][256]
        int i = idx - 196608;
        int seg = i >> 14, c = (i >> 8) & 63, k = i & 255;
        float v = (c < 40) ? w_lin[(size_t)(seg * 256 + k) * 40 + c] : 0.f;
        wlinT[i] = __float2bfloat16(v);
    }
}

// ---- gather: agg[v,:] = sum_e w_e * feat[src_e,:]  (bf16, fp32 acc) -------
// One wave per node. Wave covers EPW edges per step: lane = (es, ch) where
// es = edge slot, ch = 16B channel chunk. shfl_xor folds edge slots at end.
//   C=128: EPW=4 (es=lane>>4, ch=lane&15), row = 16 chunks x 16B
//   C=256: EPW=2 (es=lane>>5, ch=lane&31), row = 32 chunks x 16B
template <int C>
__global__ __launch_bounds__(256) void gather_bf16(
    const __hip_bfloat16* __restrict__ feat,
    const int2* __restrict__ edges,
    const int*  __restrict__ rp,
    __hip_bfloat16* __restrict__ agg, int n)
{
    const int node = (blockIdx.x * 256 + threadIdx.x) >> 6;
    const int lane = threadIdx.x & 63;
    if (node >= n) return;
    const int beg = __builtin_amdgcn_readfirstlane(rp[node]);
    const int end = __builtin_amdgcn_readfirstlane(rp[node + 1]);

    constexpr int EPW = (C == 128) ? 4 : 2;      // edges per wave-step
    const int es = (C == 128) ? (lane >> 4) : (lane >> 5);
    const int ch = (C == 128) ? (lane & 15) : (lane & 31);

    const unsigned short* fb = (const unsigned short*)feat;
    const unsigned coff = (unsigned)ch * 8;      // element offset of 16B chunk

    float acc[8] = {};
    int e = beg;
    // main loop: 2*EPW edges per iteration (two independent loads in flight)
    for (; e + 2 * EPW <= end; e += 2 * EPW) {
        int2 pa = edges[e + es];
        int2 pb = edges[e + EPW + es];
        short8 ua = *(const short8*)(fb + (unsigned)pa.x * C + coff);
        short8 ub = *(const short8*)(fb + (unsigned)pb.x * C + coff);
        float wa = __int_as_float(pa.y);
        float wb = __int_as_float(pb.y);
#pragma unroll
        for (int k = 0; k < 8; ++k)
            acc[k] = fmaf(bf2f((unsigned short)ub[k]), wb,
                     fmaf(bf2f((unsigned short)ua[k]), wa, acc[k]));
    }
    // tail: masked EPW-wide steps
    for (; e < end; e += EPW) {
        int ee = e + es;
        int2 p = edges[(ee < end) ? ee : (end - 1)];
        float w = (ee < end) ? __int_as_float(p.y) : 0.f;
        short8 u = *(const short8*)(fb + (unsigned)p.x * C + coff);
#pragma unroll
        for (int k = 0; k < 8; ++k)
            acc[k] = fmaf(bf2f((unsigned short)u[k]), w, acc[k]);
    }
    // fold edge slots
#pragma unroll
    for (int k = 0; k < 8; ++k) {
        if constexpr (C == 128) {
            acc[k] += __shfl_xor(acc[k], 16, 64);
            acc[k] += __shfl_xor(acc[k], 32, 64);
        } else {
            acc[k] += __shfl_xor(acc[k], 32, 64);
        }
    }
    if (es == 0) {
        __hip_bfloat16 o[8];
#pragma unroll
        for (int k = 0; k < 8; ++k) o[k] = __float2bfloat16(acc[k]);
        *(short8*)(agg + (size_t)node * C + coff) = *(short8*)o;
    }
}

// ---- MFMA GEMM: C = relu(A0@W0 + A1@W1 + bias), NC=256, bf16 in/out -------
__global__ __launch_bounds__(256) void gemm_mfma(
    const __hip_bfloat16* __restrict__ A0, const __hip_bfloat16* __restrict__ A1,
    const __hip_bfloat16* __restrict__ W0T, const __hip_bfloat16* __restrict__ W1T,
    const float* __restrict__ bias,
    __hip_bfloat16* __restrict__ Cmat,
    int n, int K0, int K1)
{
    __shared__ __hip_bfloat16 Asl[128 * 64];
    __shared__ __hip_bfloat16 Bsl[128 * 64];
    const int bm = blockIdx.x >> 1;
    const int bn = blockIdx.x & 1;
    const int row0 = bm * 128, col0 = bn * 128;
    const int t = threadIdx.x, lane = t & 63, wid = t >> 6;
    const int wr = wid >> 1, wc = wid & 1;

    f32x4 acc[4][4] = {};

    for (int seg = 0; seg < 2; ++seg) {
        const __hip_bfloat16* A  = seg ? A1 : A0;
        const __hip_bfloat16* WT = seg ? W1T : W0T;
        const int K = seg ? K1 : K0;
        for (int k0 = 0; k0 < K; k0 += 64) {
#pragma unroll
            for (int i = 0; i < 4; ++i) {
                int idx = i * 256 + t;
                int r = idx >> 3, c = idx & 7;
                int gr = row0 + r; if (gr >= n) gr = n - 1;
                const __hip_bfloat16* srcA =
                    A + (size_t)gr * K + k0 + ((c ^ (r & 7)) << 3);
                __builtin_amdgcn_global_load_lds(
                    (const __attribute__((address_space(1))) void*)srcA,
                    (__attribute__((address_space(3))) void*)&Asl[idx * 8], 16, 0, 0);
                const __hip_bfloat16* srcB =
                    WT + (size_t)(col0 + r) * K + k0 + ((c ^ (r & 7)) << 3);
                __builtin_amdgcn_global_load_lds(
                    (const __attribute__((address_space(1))) void*)srcB,
                    (__attribute__((address_space(3))) void*)&Bsl[idx * 8], 16, 0, 0);
            }
            __syncthreads();
#pragma unroll
            for (int kh = 0; kh < 2; ++kh) {
                const int cchunk = kh * 4 + (lane >> 4);
                short8 af[4], bfr[4];
#pragma unroll
                for (int m = 0; m < 4; ++m) {
                    int r = wr * 64 + m * 16 + (lane & 15);
                    af[m] = *(const short8*)&Asl[r * 64 + ((cchunk ^ (r & 7)) << 3)];
                }
#pragma unroll
                for (int nn = 0; nn < 4; ++nn) {
                    int r = wc * 64 + nn * 16 + (lane & 15);
                    bfr[nn] = *(const short8*)&Bsl[r * 64 + ((cchunk ^ (r & 7)) << 3)];
                }
#pragma unroll
                for (int m = 0; m < 4; ++m)
#pragma unroll
                    for (int nn = 0; nn < 4; ++nn)
                        acc[m][nn] = __builtin_amdgcn_mfma_f32_16x16x32_bf16(
                            af[m], bfr[nn], acc[m][nn], 0, 0, 0);
            }
            __syncthreads();
        }
    }

#pragma unroll
    for (int nn = 0; nn < 4; ++nn) {
        int col = col0 + wc * 64 + nn * 16 + (lane & 15);
        float b = bias[col];
#pragma unroll
        for (int m = 0; m < 4; ++m) {
#pragma unroll
            for (int rg = 0; rg < 4; ++rg) {
                int row = row0 + wr * 64 + m * 16 + ((lane >> 4) * 4) + rg;
                if (row < n) {
                    float v = fmaxf(acc[m][nn][rg] + b, 0.f);
                    Cmat[(size_t)row * 256 + col] = __float2bfloat16(v);
                }
            }
        }
    }
}

// ---- head: out = log_softmax([x1|x2] @ w_lin + b_lin), MFMA fused ---------
__global__ __launch_bounds__(256) void head_mfma(
    const __hip_bfloat16* __restrict__ X1, const __hip_bfloat16* __restrict__ X2,
    const __hip_bfloat16* __restrict__ WLT,   // [2][64][256]
    const float* __restrict__ b_lin,
    float* __restrict__ out, int n)
{
    __shared__ __hip_bfloat16 Asl[128 * 64];
    __shared__ __hip_bfloat16 Bsl[64 * 64];
    const int row0 = blockIdx.x * 128;
    const int t = threadIdx.x, lane = t & 63, wid = t >> 6;

    f32x4 acc[2][4] = {};

    for (int seg = 0; seg < 2; ++seg) {
        const __hip_bfloat16* A  = seg ? X2 : X1;
        const __hip_bfloat16* WT = WLT + seg * 64 * 256;
        for (int k0 = 0; k0 < 256; k0 += 64) {
#pragma unroll
            for (int i = 0; i < 4; ++i) {
                int idx = i * 256 + t;
                int r = idx >> 3, c = idx & 7;
                int gr = row0 + r; if (gr >= n) gr = n - 1;
                const __hip_bfloat16* srcA =
                    A + (size_t)gr * 256 + k0 + ((c ^ (r & 7)) << 3);
                __builtin_amdgcn_global_load_lds(
                    (const __attribute__((address_space(1))) void*)srcA,
                    (__attribute__((address_space(3))) void*)&Asl[idx * 8], 16, 0, 0);
            }
#pragma unroll
            for (int i = 0; i < 2; ++i) {
                int idx = i * 256 + t;
                int r = idx >> 3, c = idx & 7;
                const __hip_bfloat16* srcB =
                    WT + (size_t)r * 256 + k0 + ((c ^ (r & 7)) << 3);
                __builtin_amdgcn_global_load_lds(
                    (const __attribute__((address_space(1))) void*)srcB,
                    (__attribute__((address_space(3))) void*)&Bsl[idx * 8], 16, 0, 0);
            }
            __syncthreads();
#pragma unroll
            for (int kh = 0; kh < 2; ++kh) {
                const int cchunk = kh * 4 + (lane >> 4);
                short8 af[2], bfr[4];
#pragma unroll
                for (int m = 0; m < 2; ++m) {
                    int r = wid * 32 + m * 16 + (lane & 15);
                    af[m] = *(const short8*)&Asl[r * 64 + ((cchunk ^ (r & 7)) << 3)];
                }
#pragma unroll
                for (int nn = 0; nn < 4; ++nn) {
                    int r = nn * 16 + (lane & 15);
                    bfr[nn] = *(const short8*)&Bsl[r * 64 + ((cchunk ^ (r & 7)) << 3)];
                }
#pragma unroll
                for (int m = 0; m < 2; ++m)
#pragma unroll
                    for (int nn = 0; nn < 4; ++nn)
                        acc[m][nn] = __builtin_amdgcn_mfma_f32_16x16x32_bf16(
                            af[m], bfr[nn], acc[m][nn], 0, 0, 0);
            }
            __syncthreads();
        }
    }

    const int cl = lane & 15;
    float bb[4];
#pragma unroll
    for (int nn = 0; nn < 4; ++nn) {
        int col = nn * 16 + cl;
        bb[nn] = (col < 40) ? b_lin[col] : 0.f;
    }
#pragma unroll
    for (int m = 0; m < 2; ++m) {
#pragma unroll
        for (int rg = 0; rg < 4; ++rg) {
            float v[4];
            float mx = -1e30f;
#pragma unroll
            for (int nn = 0; nn < 4; ++nn) {
                int col = nn * 16 + cl;
                v[nn] = acc[m][nn][rg] + bb[nn];
                if (col < 40) mx = fmaxf(mx, v[nn]);
            }
#pragma unroll
            for (int off = 1; off < 16; off <<= 1)
                mx = fmaxf(mx, __shfl_xor(mx, off, 64));
            float s = 0.f;
#pragma unroll
            for (int nn = 0; nn < 4; ++nn) {
                int col = nn * 16 + cl;
                if (col < 40) s += expf(v[nn] - mx);
            }
#pragma unroll
            for (int off = 1; off < 16; off <<= 1)
                s += __shfl_xor(s, off, 64);
            float ls = logf(s);
            int row = row0 + wid * 32 + m * 16 + ((lane >> 4) * 4) + rg;
            if (row < n) {
#pragma unroll
                for (int nn = 0; nn < 4; ++nn) {
                    int col = nn * 16 + cl;
                    if (col < 40)
                        out[(size_t)row * 40 + col] = v[nn] - mx - ls;
                }
            }
        }
    }
}

// ---------------------------------------------------------------------------
extern "C" void kernel_launch(void* const* d_in, const int* in_sizes, int n_in,
                              void* d_out, int out_size, void* d_ws, size_t ws_size,
                              hipStream_t stream)
{
    const float* x       = (const float*)d_in[0];
    const int*   ei      = (const int*)  d_in[1];
    const float* ew      = (const float*)d_in[2];
    const float* w1_rel  = (const float*)d_in[3];
    const float* b1      = (const float*)d_in[4];
    const float* w1_root = (const float*)d_in[5];
    const float* w2_rel  = (const float*)d_in[6];
    const float* b2      = (const float*)d_in[7];
    const float* w2_root = (const float*)d_in[8];
    const float* w_lin   = (const float*)d_in[9];
    const float* b_lin   = (const float*)d_in[10];
    float* out = (float*)d_out;

    const int N = in_sizes[0] / 128;   // 50000
    const int E = in_sizes[2];         // 800000

    auto align = [](char*& p, size_t bytes) {
        char* r = p;
        p += (bytes + 255) & ~(size_t)255;
        return r;
    };
    char* wp = (char*)d_ws;
    __hip_bfloat16* xb     = (__hip_bfloat16*)align(wp, (size_t)N * 128 * 2);
    __hip_bfloat16* agg1b  = (__hip_bfloat16*)align(wp, (size_t)N * 128 * 2);
    __hip_bfloat16* x1b    = (__hip_bfloat16*)align(wp, (size_t)N * 256 * 2);
    __hip_bfloat16* agg2b  = (__hip_bfloat16*)align(wp, (size_t)N * 256 * 2);
    __hip_bfloat16* x2b    = (__hip_bfloat16*)align(wp, (size_t)N * 256 * 2);
    __hip_bfloat16* w1relT  = (__hip_bfloat16*)align(wp, 256 * 128 * 2);
    __hip_bfloat16* w1rootT = (__hip_bfloat16*)align(wp, 256 * 128 * 2);
    __hip_bfloat16* w2relT  = (__hip_bfloat16*)align(wp, 256 * 256 * 2);
    __hip_bfloat16* w2rootT = (__hip_bfloat16*)align(wp, 256 * 256 * 2);
    __hip_bfloat16* wlinT   = (__hip_bfloat16*)align(wp, 2 * 64 * 256 * 2);
    int*   counts  = (int*)align(wp, (size_t)N * 4);
    int*   row_ptr = (int*)align(wp, (size_t)(N + 1) * 4);
    int*   cursor  = (int*)align(wp, (size_t)N * 4);
    int*   bsum    = (int*)align(wp, 256 * 4);
    int*   bpre    = (int*)align(wp, 256 * 4);
    int2*  edges   = (int2*)align(wp, (size_t)E * 8);

    const int eb = (E + 255) / 256;
    const int nb = (N + 255) / 256;   // 196 <= 256

    hipMemsetAsync(counts, 0, (size_t)N * 4, stream);
    const int NX8 = N * 128 / 8;       // 800000
    {
        long long total = (long long)E + NX8 + 229376;
        int blocks = (int)((total + 255) / 256);
        prep_all<<<blocks, 256, 0, stream>>>(
            ei, counts, E, x, xb, NX8,
            w1_rel, w1_root, w2_rel, w2_root, w_lin,
            w1relT, w1rootT, w2relT, w2rootT, wlinT);
    }
    scan_block_sums<<<nb, 256, 0, stream>>>(counts, bsum, N);
    scan_bsum<<<1, 256, 0, stream>>>(bsum, bpre, nb);
    scan_final<<<nb, 256, 0, stream>>>(counts, bpre, row_ptr, cursor, N, E);
    fill_kernel<<<eb, 256, 0, stream>>>(ei, ew, cursor, edges, E);

    const int gather_blocks = (N * 64 + 255) / 256;
    const int gemm_grid     = ((N + 127) / 128) * 2;
    const int head_grid     = (N + 127) / 128;

    // layer 1
    gather_bf16<128><<<gather_blocks, 256, 0, stream>>>(
        xb, edges, row_ptr, agg1b, N);
    gemm_mfma<<<gemm_grid, 256, 0, stream>>>(
        agg1b, xb, w1relT, w1rootT, b1, x1b, N, 128, 128);
    // layer 2
    gather_bf16<256><<<gather_blocks, 256, 0, stream>>>(
        x1b, edges, row_ptr, agg2b, N);
    gemm_mfma<<<gemm_grid, 256, 0, stream>>>(
        agg2b, x1b, w2relT, w2rootT, b2, x2b, N, 256, 256);
    // head
    head_mfma<<<head_grid, 256, 0, stream>>>(x1b, x2b, wlinT, b_lin, out, N);
}